// Round 1
// baseline (225.550 us; speedup 1.0000x reference)
//
#include <hip/hip_runtime.h>
#include <hip/hip_bf16.h>

// Problem constants (match reference):
//   B=8, N=4096, F_IN=256, F_OUT=256, E=131072
// out[b,i,f] = (1/deg[i]) * sum_{j in nbr(i)} (x[b,j,:] @ W)[f] + bias[f]
// adj[src,dst]=1 with duplicate edges collapsing; deg[i] = popcount(row i) + 1e-6.

#define GC_B     8
#define GC_N     4096
#define GC_FIN   256
#define GC_FOUT  256
#define GC_E     131072
#define GC_M     (GC_B * GC_N)          // 32768 rows of x (flattened b,n)
#define MASK_WPR (GC_N / 32)            // 128 u32 words per adjacency row

// ---------------------------------------------------------------------------
// Kernel 1: build dedup bitmask.  mask[src*128 + dst/32] |= bit(dst%32)
// ---------------------------------------------------------------------------
__global__ void build_mask_kernel(const int* __restrict__ ei,
                                  unsigned* __restrict__ mask) {
    int e = blockIdx.x * blockDim.x + threadIdx.x;
    if (e < GC_E) {
        int s = ei[e];
        int d = ei[GC_E + e];
        atomicOr(&mask[s * MASK_WPR + (d >> 5)], 1u << (d & 31));
    }
}

// ---------------------------------------------------------------------------
// Kernel 2: xt = x @ W   (fp32, 64x64 tile, K-chunks of 16, 4x4 per thread)
// M=32768, K=256, Nout=256
// ---------------------------------------------------------------------------
__global__ __launch_bounds__(256) void gemm_xw_kernel(
        const float* __restrict__ X, const float* __restrict__ W,
        float* __restrict__ XT) {
    const int K = GC_FIN, Nout = GC_FOUT;
    __shared__ float As[16][64];   // [k][m] (transposed for fast m-reads)
    __shared__ float Bs[16][64];   // [k][n]

    const int m0 = blockIdx.x * 64;
    const int n0 = blockIdx.y * 64;
    const int t  = threadIdx.x;
    const int tx = t & 15;         // output col group
    const int ty = t >> 4;         // output row group

    float c[4][4] = {};

    for (int k0 = 0; k0 < K; k0 += 16) {
        // Load A tile: 64 rows x 16 k. thread t: row m=t/4, k-quad=(t%4)*4
        {
            const int m  = t >> 2;
            const int kq = (t & 3) << 2;
            const float4 a = *(const float4*)&X[(size_t)(m0 + m) * K + k0 + kq];
            As[kq + 0][m] = a.x;
            As[kq + 1][m] = a.y;
            As[kq + 2][m] = a.z;
            As[kq + 3][m] = a.w;
            // Load B tile: 16 k x 64 n. thread t: k=t/16, n-quad=(t%16)*4
            const int kb = t >> 4;
            const int nq = (t & 15) << 2;
            *(float4*)&Bs[kb][nq] =
                *(const float4*)&W[(size_t)(k0 + kb) * Nout + n0 + nq];
        }
        __syncthreads();
        #pragma unroll
        for (int kk = 0; kk < 16; kk++) {
            const float4 av = *(const float4*)&As[kk][ty * 4];
            const float4 bv = *(const float4*)&Bs[kk][tx * 4];
            const float a[4] = {av.x, av.y, av.z, av.w};
            const float b[4] = {bv.x, bv.y, bv.z, bv.w};
            #pragma unroll
            for (int ii = 0; ii < 4; ii++)
                #pragma unroll
                for (int jj = 0; jj < 4; jj++)
                    c[ii][jj] += a[ii] * b[jj];
        }
        __syncthreads();
    }

    #pragma unroll
    for (int ii = 0; ii < 4; ii++) {
        float4 v = make_float4(c[ii][0], c[ii][1], c[ii][2], c[ii][3]);
        *(float4*)&XT[(size_t)(m0 + ty * 4 + ii) * Nout + n0 + tx * 4] = v;
    }
}

// ---------------------------------------------------------------------------
// Kernel 3: aggregate.  One block per (b,i): scan mask row -> LDS neighbor
// list, then thread f accumulates xt[b, j, f] over neighbors j.
// ---------------------------------------------------------------------------
__global__ __launch_bounds__(256) void aggregate_kernel(
        const float* __restrict__ XT, const unsigned* __restrict__ mask,
        const float* __restrict__ bias, float* __restrict__ out) {
    __shared__ int nbrs[GC_N];     // worst-case full row (16 KB)
    __shared__ int cnt;

    const int bn = blockIdx.x;           // b*N + i
    const int i  = bn & (GC_N - 1);
    const int b  = bn >> 12;             // / 4096

    if (threadIdx.x == 0) cnt = 0;
    __syncthreads();

    if (threadIdx.x < MASK_WPR) {
        unsigned w = mask[i * MASK_WPR + threadIdx.x];
        const int base = threadIdx.x * 32;
        while (w) {
            const int bit = __builtin_ctz(w);
            w &= w - 1;
            const int pos = atomicAdd(&cnt, 1);
            nbrs[pos] = base + bit;
        }
    }
    __syncthreads();

    const int deg = cnt;
    const float inv = 1.0f / ((float)deg + 1e-6f);
    const int f = threadIdx.x;           // F_OUT == blockDim.x == 256

    const float* xb = XT + (size_t)b * GC_N * GC_FOUT;
    float acc = 0.0f;
    for (int k = 0; k < deg; k++) {
        acc += xb[(size_t)nbrs[k] * GC_FOUT + f];
    }
    out[(size_t)bn * GC_FOUT + f] = acc * inv + bias[f];
}

// ---------------------------------------------------------------------------
extern "C" void kernel_launch(void* const* d_in, const int* in_sizes, int n_in,
                              void* d_out, int out_size, void* d_ws, size_t ws_size,
                              hipStream_t stream) {
    const float* x      = (const float*)d_in[0];   // (8, 4096, 256)
    const int*   ei     = (const int*)d_in[1];     // (2, 131072)
    const float* weight = (const float*)d_in[2];   // (256, 256)
    const float* bias   = (const float*)d_in[3];   // (256,)
    float*       out    = (float*)d_out;           // (8, 4096, 256)

    // Workspace layout: [ xt : M*FOUT floats = 32 MiB ][ mask : 2 MiB ]
    float*    xt   = (float*)d_ws;
    unsigned* mask = (unsigned*)((char*)d_ws + (size_t)GC_M * GC_FOUT * sizeof(float));

    // 1) zero the dedup bitmask
    hipMemsetAsync(mask, 0, (size_t)GC_N * MASK_WPR * sizeof(unsigned), stream);

    // 2) build bitmask from edges
    build_mask_kernel<<<(GC_E + 255) / 256, 256, 0, stream>>>(ei, mask);

    // 3) xt = x @ W
    dim3 ggrid(GC_M / 64, GC_FOUT / 64);
    gemm_xw_kernel<<<ggrid, 256, 0, stream>>>(x, weight, xt);

    // 4) aggregate + bias
    aggregate_kernel<<<GC_B * GC_N, 256, 0, stream>>>(xt, mask, bias, out);
}